// Round 1
// baseline (340.024 us; speedup 1.0000x reference)
//
#include <hip/hip_runtime.h>
#include <cstdint>
#include <cstddef>

// ---------------------------------------------------------------------------
// Flow_24429773980225 — algebraically reduced:
//   s[b,n]   = <Q[b,n,:], K[b,n,:]>           (softmax over b only; diag of att)
//   diag     = softmax_b(s/128)
//   VW       = V @ WO^T                        (diag row-scale commutes out)
//   out[b,n] = <node_t[b,n,:], vE> + <gelu(diag*VW + bO), vN> + c0
// where vE = WA_w · WE_w, vN = WA_w · WN_w, c0 = <wa,WE_b>+<wa,WN_b>+WA_b.
// 4 bf16 MFMA GEMMs [16384,1024]x[1024,1024]^T + memory passes.
// ---------------------------------------------------------------------------

typedef __attribute__((ext_vector_type(8))) short bfx8;   // 8 bf16 (4 VGPR)
typedef __attribute__((ext_vector_type(4))) short s16x4;  // 4 bf16 (8B)
typedef __attribute__((ext_vector_type(4))) float f32x4;  // MFMA acc

#define N_SEQ 2048
#define H_DIM 1024
#define M_TOT 16384   // B*N = 8*2048

__device__ __forceinline__ unsigned short f2bf(float f) {
  unsigned int u = __float_as_uint(f);
  return (unsigned short)((u + 0x7fffu + ((u >> 16) & 1u)) >> 16);  // RNE
}
__device__ __forceinline__ float bf2f(short s) {
  return __uint_as_float(((unsigned int)(unsigned short)s) << 16);
}
__device__ __forceinline__ float gelu_exact(float g) {
  return 0.5f * g * (1.0f + erff(g * 0.70710678118654752f));
}
__device__ __forceinline__ void gload16(const void* g, void* l) {
  __builtin_amdgcn_global_load_lds(
      (const __attribute__((address_space(1))) unsigned int*)g,
      (__attribute__((address_space(3))) unsigned int*)(unsigned int)(uintptr_t)l,
      16, 0, 0);
}
// 256-thread block sum; every thread returns the total.
__device__ __forceinline__ float blk_sum(float v, float* red, int t) {
#pragma unroll
  for (int o = 32; o > 0; o >>= 1) v += __shfl_down(v, o, 64);
  __syncthreads();                       // protect red[] from previous use
  if ((t & 63) == 0) red[t >> 6] = v;
  __syncthreads();
  return red[0] + red[1] + red[2] + red[3];
}

// --------------------------- small precomputes -----------------------------
// y=0: vE[h] = sum_o wa[o]*WE[o,h]; y=1: vN from WN; y=2 (block 0): c0 scalar.
__global__ __launch_bounds__(256) void colred_kernel(
    const float* __restrict__ WE, const float* __restrict__ WN,
    const float* __restrict__ wa, const float* __restrict__ WEb,
    const float* __restrict__ WNb, const float* __restrict__ WAb,
    float* __restrict__ vE, float* __restrict__ vN, float* __restrict__ c0) {
  if (blockIdx.y < 2) {
    const float* M = blockIdx.y ? WN : WE;
    float* dst = blockIdx.y ? vN : vE;
    int h = blockIdx.x * 256 + threadIdx.x;  // 4 blocks x 256 = 1024
    float a = 0.f;
    for (int o = 0; o < 1024; ++o) a += wa[o] * M[(size_t)o * 1024 + h];
    dst[h] = a;
  } else if (blockIdx.x == 0) {
    int t = threadIdx.x;
    float a = 0.f;
    for (int i = t; i < 1024; i += 256) a += wa[i] * (WEb[i] + WNb[i]);
#pragma unroll
    for (int o = 32; o > 0; o >>= 1) a += __shfl_down(a, o, 64);
    __shared__ float r4[4];
    if ((t & 63) == 0) r4[t >> 6] = a;
    __syncthreads();
    if (t == 0) c0[0] = r4[0] + r4[1] + r4[2] + r4[3] + WAb[0];
  }
}

// Convert WQ,WK,WV,WO (f32 1024x1024 each) to bf16, contiguous at dst.
__global__ __launch_bounds__(256) void cvt_w_kernel(
    const float* __restrict__ WQ, const float* __restrict__ WK,
    const float* __restrict__ WV, const float* __restrict__ WO,
    short* __restrict__ dst) {
  size_t id = (size_t)blockIdx.x * 256 + threadIdx.x;  // 2048 blocks
  int mat = (int)(id >> 17);                           // 131072 threads/mat
  size_t off = (id & 131071) * 8;
  const float* src = mat == 0 ? WQ : mat == 1 ? WK : mat == 2 ? WV : WO;
  float4 v0 = *(const float4*)(src + off);
  float4 v1 = *(const float4*)(src + off + 4);
  bfx8 o;
  o[0] = (short)f2bf(v0.x); o[1] = (short)f2bf(v0.y);
  o[2] = (short)f2bf(v0.z); o[3] = (short)f2bf(v0.w);
  o[4] = (short)f2bf(v1.x); o[5] = (short)f2bf(v1.y);
  o[6] = (short)f2bf(v1.z); o[7] = (short)f2bf(v1.w);
  *(bfx8*)(dst + (size_t)mat * 1048576 + off) = o;
}

// Convert node_t/node_next to bf16; for node_t also xe[row] = <row, vE>.
__global__ __launch_bounds__(128) void cvt_in_kernel(
    const float* __restrict__ nt, const float* __restrict__ nn,
    const float* __restrict__ vE, short* __restrict__ xt,
    short* __restrict__ xn, float* __restrict__ xe) {
  int row = blockIdx.x, which = blockIdx.y, t = threadIdx.x;  // 128 thr x 8 el
  const float* src = (which ? nn : nt) + (size_t)row * 1024 + t * 8;
  float4 v0 = *(const float4*)src;
  float4 v1 = *(const float4*)(src + 4);
  bfx8 o;
  o[0] = (short)f2bf(v0.x); o[1] = (short)f2bf(v0.y);
  o[2] = (short)f2bf(v0.z); o[3] = (short)f2bf(v0.w);
  o[4] = (short)f2bf(v1.x); o[5] = (short)f2bf(v1.y);
  o[6] = (short)f2bf(v1.z); o[7] = (short)f2bf(v1.w);
  *(bfx8*)((which ? xn : xt) + (size_t)row * 1024 + t * 8) = o;
  if (which == 0) {
    const float4* ve = (const float4*)(vE + t * 8);
    float4 e0 = ve[0], e1 = ve[1];
    float a = v0.x * e0.x + v0.y * e0.y + v0.z * e0.z + v0.w * e0.w +
              v1.x * e1.x + v1.y * e1.y + v1.z * e1.z + v1.w * e1.w;
#pragma unroll
    for (int off = 32; off > 0; off >>= 1) a += __shfl_down(a, off, 64);
    __shared__ float r2[2];
    if ((t & 63) == 0) r2[t >> 6] = a;
    __syncthreads();
    if (t == 0) xe[row] = r2[0] + r2[1];
  }
}

// ------------------------------ main GEMM ----------------------------------
// D[m,n] = sum_k A[m,k]*B[n,k] (+bias[n]); A:[16384,1024] bf16, B:[1024,1024]
// bf16 row-major, D bf16. 128x128 tile, BK=64, 4 waves (2x2, 64x64 each),
// mfma_f32_16x16x32_bf16, global_load_lds width 16 (m97 structure).
__global__ __launch_bounds__(256) void gemm_bt(
    const short* __restrict__ A, const short* __restrict__ B,
    const float* __restrict__ bias, short* __restrict__ D) {
  __shared__ short sA[128 * 64];
  __shared__ short sB[128 * 64];
  int tid = threadIdx.x;
  int lane = tid & 63, w = tid >> 6;
  int wm = w >> 1, wn = w & 1;
  int bx = blockIdx.x, by = blockIdx.y;
  f32x4 acc[4][4] = {};
  int lrow = lane & 15, lk = (lane >> 4) * 8;
  int srow = lane >> 3, scol = (lane & 7) * 8;
  const short* Ag = A + (size_t)by * 128 * 1024;
  const short* Bg = B + (size_t)bx * 128 * 1024;
  for (int k0 = 0; k0 < 1024; k0 += 64) {
#pragma unroll
    for (int i = 0; i < 4; ++i) {
      int c = w * 4 + i;  // 16 chunks of 8 rows x 64 cols; lds = base+lane*16
      gload16(Ag + (size_t)(c * 8 + srow) * 1024 + k0 + scol, sA + c * 512);
      gload16(Bg + (size_t)(c * 8 + srow) * 1024 + k0 + scol, sB + c * 512);
    }
    __syncthreads();
#pragma unroll
    for (int kk = 0; kk < 64; kk += 32) {
      bfx8 af[4], bf[4];
#pragma unroll
      for (int mi = 0; mi < 4; ++mi)
        af[mi] = *(const bfx8*)(sA + (wm * 64 + mi * 16 + lrow) * 64 + kk + lk);
#pragma unroll
      for (int nj = 0; nj < 4; ++nj)
        bf[nj] = *(const bfx8*)(sB + (wn * 64 + nj * 16 + lrow) * 64 + kk + lk);
#pragma unroll
      for (int mi = 0; mi < 4; ++mi)
#pragma unroll
        for (int nj = 0; nj < 4; ++nj)
          acc[mi][nj] = __builtin_amdgcn_mfma_f32_16x16x32_bf16(
              af[mi], bf[nj], acc[mi][nj], 0, 0, 0);
    }
    __syncthreads();
  }
  int r0 = by * 128 + wm * 64, cb = bx * 128 + wn * 64;
#pragma unroll
  for (int mi = 0; mi < 4; ++mi) {
#pragma unroll
    for (int nj = 0; nj < 4; ++nj) {
      int col = cb + nj * 16 + lrow;
      float bv = bias ? bias[col] : 0.0f;
#pragma unroll
      for (int r = 0; r < 4; ++r) {
        int row = r0 + mi * 16 + (lane >> 4) * 4 + r;
        D[(size_t)row * 1024 + col] = (short)f2bf(acc[mi][nj][r] + bv);
      }
    }
  }
}

// Per n: s[b] = <Q[row],K[row]>, softmax_b(s/128) -> diag.
__global__ __launch_bounds__(256) void sdiag_kernel(
    const short* __restrict__ Qb, const short* __restrict__ Kb,
    float* __restrict__ dg) {
  int n = blockIdx.x, t = threadIdx.x;
  __shared__ float red[4];
  float s[8];
#pragma unroll
  for (int b = 0; b < 8; ++b) {
    size_t row = (size_t)b * N_SEQ + n;
    s16x4 qv = *(const s16x4*)(Qb + row * 1024 + t * 4);
    s16x4 kv = *(const s16x4*)(Kb + row * 1024 + t * 4);
    float a = bf2f(qv[0]) * bf2f(kv[0]) + bf2f(qv[1]) * bf2f(kv[1]) +
              bf2f(qv[2]) * bf2f(kv[2]) + bf2f(qv[3]) * bf2f(kv[3]);
    s[b] = blk_sum(a, red, t);
  }
  float m = s[0];
#pragma unroll
  for (int b = 1; b < 8; ++b) m = fmaxf(m, s[b]);
  float e[8], sum = 0.f;
#pragma unroll
  for (int b = 0; b < 8; ++b) {
    e[b] = expf((s[b] - m) * (1.0f / 128.0f));
    sum += e[b];
  }
  float inv = 1.0f / sum;
  if (t == 0) {
#pragma unroll
    for (int b = 0; b < 8; ++b) dg[(size_t)b * N_SEQ + n] = e[b] * inv;
  }
}

// out[row] = xe[row] + c0 + sum_c gelu(diag*VW[row,c] + bO[c]) * vN[c]
__global__ __launch_bounds__(256) void out_kernel(
    const short* __restrict__ VW, const float* __restrict__ dg,
    const float* __restrict__ xe, const float* __restrict__ vN,
    const float* __restrict__ bO, const float* __restrict__ c0p,
    float* __restrict__ out) {
  int n = blockIdx.x, t = threadIdx.x;
  __shared__ float red[4];
  float4 bo = ((const float4*)bO)[t];
  float4 vn = ((const float4*)vN)[t];
  float c0 = c0p[0];
#pragma unroll
  for (int b = 0; b < 8; ++b) {
    size_t row = (size_t)b * N_SEQ + n;
    float d = dg[row];
    s16x4 vv = *(const s16x4*)(VW + row * 1024 + t * 4);
    float g, a = 0.f;
    g = fmaf(d, bf2f(vv[0]), bo.x); a += gelu_exact(g) * vn.x;
    g = fmaf(d, bf2f(vv[1]), bo.y); a += gelu_exact(g) * vn.y;
    g = fmaf(d, bf2f(vv[2]), bo.z); a += gelu_exact(g) * vn.z;
    g = fmaf(d, bf2f(vv[3]), bo.w); a += gelu_exact(g) * vn.w;
    float tot = blk_sum(a, red, t);
    if (t == 0) out[row] = xe[row] + c0 + tot;
  }
}

// ---------------------------------------------------------------------------
extern "C" void kernel_launch(void* const* d_in, const int* in_sizes, int n_in,
                              void* d_out, int out_size, void* d_ws,
                              size_t ws_size, hipStream_t stream) {
  const float* nt  = (const float*)d_in[0];
  const float* nn  = (const float*)d_in[1];
  const float* WQ  = (const float*)d_in[2];
  const float* bQ  = (const float*)d_in[3];
  const float* WK  = (const float*)d_in[4];
  const float* bK  = (const float*)d_in[5];
  const float* WV  = (const float*)d_in[6];
  const float* bV  = (const float*)d_in[7];
  const float* WO  = (const float*)d_in[8];
  const float* bO  = (const float*)d_in[9];
  const float* WE  = (const float*)d_in[10];
  const float* WEb = (const float*)d_in[11];
  const float* WN  = (const float*)d_in[12];
  const float* WNb = (const float*)d_in[13];
  const float* wa  = (const float*)d_in[14];
  const float* WAb = (const float*)d_in[15];
  float* out = (float*)d_out;

  char* w = (char*)d_ws;
  size_t o = 0;
  const size_t BIG = (size_t)M_TOT * 1024 * 2;  // 33.55 MB bf16 token matrix
  short* xt = (short*)(w + o); o += BIG;
  short* xn = (short*)(w + o); o += BIG;
  short* Qb = (short*)(w + o); o += BIG;
  short* Kb = (short*)(w + o); o += BIG;  // later reused as VW
  short* Vb = (short*)(w + o); o += BIG;
  short* wq = (short*)(w + o); o += 2097152;
  short* wk = (short*)(w + o); o += 2097152;
  short* wv = (short*)(w + o); o += 2097152;
  short* wo = (short*)(w + o); o += 2097152;
  float* vE = (float*)(w + o); o += 4096;
  float* vN = (float*)(w + o); o += 4096;
  float* xe = (float*)(w + o); o += 65536;
  float* dg = (float*)(w + o); o += 65536;
  float* c0 = (float*)(w + o); o += 256;
  (void)ws_size; (void)in_sizes; (void)n_in; (void)out_size;

  colred_kernel<<<dim3(4, 3), 256, 0, stream>>>(WE, WN, wa, WEb, WNb, WAb,
                                                vE, vN, c0);
  cvt_w_kernel<<<2048, 256, 0, stream>>>(WQ, WK, WV, WO, wq);
  cvt_in_kernel<<<dim3(16384, 2), 128, 0, stream>>>(nt, nn, vE, xt, xn, xe);
  gemm_bt<<<dim3(8, 128), 256, 0, stream>>>(xt, wq, bQ, Qb);      // Q
  gemm_bt<<<dim3(8, 128), 256, 0, stream>>>(xn, wk, bK, Kb);      // K
  gemm_bt<<<dim3(8, 128), 256, 0, stream>>>(xn, wv, bV, Vb);      // V
  sdiag_kernel<<<2048, 256, 0, stream>>>(Qb, Kb, dg);             // diag
  gemm_bt<<<dim3(8, 128), 256, 0, stream>>>(Vb, wo, nullptr, Kb); // VW (alias)
  out_kernel<<<2048, 256, 0, stream>>>(Kb, dg, xe, vN, bO, c0, out);
}

// Round 2
// 221.364 us; speedup vs baseline: 1.5360x; 1.5360x over previous
//
#include <hip/hip_runtime.h>
#include <cstdint>
#include <cstddef>

// ---------------------------------------------------------------------------
// Flow_24429773980225 — round 2: algebraic GEMM-halving + XCD swizzle.
//   s[r]  = <node_t[r], t[r]> + <x_n[r], uK> + c1,  t = x_n@M1^T + uQ
//   M1    = WQ^T WK,  uQ = WQ^T bK,  uK = WK^T bQ,  c1 = <bQ,bK>
//   dg    = softmax_b(s/128)
//   vw    = x_n@M2^T + bvw,  M2 = WO·WV,  bvw = WO·bV
//   out[r]= <node_t[r], vE> + c0 + sum_c gelu(dg[r]*vw[r,c] + bO[c])·vN[c]
//   vE = WA·WE, vN = WA·WN, c0 = <wa, WE_b+WN_b> + WA_b
// One fused [16384,1024]x[2048,1024]^T bf16 MFMA GEMM; t-half's epilogue
// computes the s row-dot in-register (never materialized).
// ---------------------------------------------------------------------------

typedef __attribute__((ext_vector_type(8))) short bfx8;   // 8 bf16
typedef __attribute__((ext_vector_type(4))) short s16x4;  // 4 bf16
typedef __attribute__((ext_vector_type(4))) float f32x4;  // MFMA acc

#define N_SEQ 2048
#define M_TOT 16384   // B*N

__device__ __forceinline__ unsigned short f2bf(float f) {
  unsigned int u = __float_as_uint(f);
  return (unsigned short)((u + 0x7fffu + ((u >> 16) & 1u)) >> 16);  // RNE
}
__device__ __forceinline__ float bf2f(short s) {
  return __uint_as_float(((unsigned int)(unsigned short)s) << 16);
}
__device__ __forceinline__ float gelu_exact(float g) {
  return 0.5f * g * (1.0f + erff(g * 0.70710678118654752f));
}
__device__ __forceinline__ void gload16(const void* g, void* l) {
  __builtin_amdgcn_global_load_lds(
      (const __attribute__((address_space(1))) unsigned int*)g,
      (__attribute__((address_space(3))) unsigned int*)(unsigned int)(uintptr_t)l,
      16, 0, 0);
}
// 256-thread block sum; every thread returns the total.
__device__ __forceinline__ float blk_sum(float v, float* red, int t) {
#pragma unroll
  for (int o = 32; o > 0; o >>= 1) v += __shfl_down(v, o, 64);
  __syncthreads();
  if ((t & 63) == 0) red[t >> 6] = v;
  __syncthreads();
  return red[0] + red[1] + red[2] + red[3];
}

// --------------------------- small precomputes -----------------------------
// y 0..3: column reductions dst[h] = sum_o wvec[o]*M[o,h]:
//   (WE,wa)->vE  (WN,wa)->vN  (WQ,bK)->uQ(=bias2 lo)  (WK,bQ)->uK
// y==4: x==0 -> c0, x==1 -> c1.
__global__ __launch_bounds__(256) void colred_kernel(
    const float* __restrict__ WE, const float* __restrict__ WN,
    const float* __restrict__ WQ, const float* __restrict__ WK,
    const float* __restrict__ wa, const float* __restrict__ bQ,
    const float* __restrict__ bK, const float* __restrict__ WEb,
    const float* __restrict__ WNb, const float* __restrict__ WAb,
    float* __restrict__ vE, float* __restrict__ vN,
    float* __restrict__ uQ, float* __restrict__ uK,
    float* __restrict__ c0, float* __restrict__ c1) {
  int y = blockIdx.y;
  if (y < 4) {
    const float* M = y == 0 ? WE : y == 1 ? WN : y == 2 ? WQ : WK;
    const float* wv = (y < 2) ? wa : (y == 2 ? bK : bQ);
    float* dst = y == 0 ? vE : y == 1 ? vN : y == 2 ? uQ : uK;
    int h = blockIdx.x * 256 + threadIdx.x;  // 4 blocks x 256
    float a = 0.f;
    for (int o = 0; o < 1024; ++o) a += wv[o] * M[(size_t)o * 1024 + h];
    dst[h] = a;
  } else if (blockIdx.x < 2) {
    int t = threadIdx.x;
    float a = 0.f;
    if (blockIdx.x == 0)
      for (int i = t; i < 1024; i += 256) a += wa[i] * (WEb[i] + WNb[i]);
    else
      for (int i = t; i < 1024; i += 256) a += bQ[i] * bK[i];
#pragma unroll
    for (int o = 32; o > 0; o >>= 1) a += __shfl_down(a, o, 64);
    __shared__ float r4[4];
    if ((t & 63) == 0) r4[t >> 6] = a;
    __syncthreads();
    if (t == 0) {
      float tot = r4[0] + r4[1] + r4[2] + r4[3];
      if (blockIdx.x == 0) c0[0] = tot + WAb[0];
      else c1[0] = tot;
    }
  }
}

// bvw[r] = <WO[r,:], bV>   (written to bias2+1024)
__global__ __launch_bounds__(256) void rowdot_kernel(
    const float* __restrict__ WO, const float* __restrict__ bV,
    float* __restrict__ bvw) {
  int r = blockIdx.x, t = threadIdx.x;
  __shared__ float red[4];
  float4 wv = ((const float4*)(WO + (size_t)r * 1024))[t];
  float4 bv = ((const float4*)bV)[t];
  float a = wv.x * bv.x + wv.y * bv.y + wv.z * bv.z + wv.w * bv.w;
  float tot = blk_sum(a, red, t);
  if (t == 0) bvw[r] = tot;
}

// z 0..2: bf16 TRANSPOSED converts WQ->wqT, WK->wkT, WV->wvT; z==3: WO plain.
__global__ __launch_bounds__(256) void cvt_wT_kernel(
    const float* __restrict__ WQ, const float* __restrict__ WK,
    const float* __restrict__ WV, const float* __restrict__ WO,
    short* __restrict__ wqT, short* __restrict__ wkT,
    short* __restrict__ wvT, short* __restrict__ wo) {
  int bi = blockIdx.x, bj = blockIdx.y, z = blockIdx.z, t = threadIdx.x;
  const float* src = z == 0 ? WQ : z == 1 ? WK : z == 2 ? WV : WO;
  if (z == 3) {
#pragma unroll
    for (int i = 0; i < 16; ++i) {
      int lin = i * 256 + t, r = lin >> 6, c = lin & 63;
      size_t idx = (size_t)(bi * 64 + r) * 1024 + bj * 64 + c;
      wo[idx] = (short)f2bf(src[idx]);
    }
    return;
  }
  __shared__ short tile[64][65];
  short* dst = z == 0 ? wqT : z == 1 ? wkT : wvT;
#pragma unroll
  for (int i = 0; i < 16; ++i) {
    int lin = i * 256 + t, r = lin >> 6, c = lin & 63;
    tile[r][c] = (short)f2bf(src[(size_t)(bi * 64 + r) * 1024 + bj * 64 + c]);
  }
  __syncthreads();
#pragma unroll
  for (int i = 0; i < 16; ++i) {
    int lin = i * 256 + t, r = lin >> 6, c = lin & 63;
    dst[(size_t)(bj * 64 + r) * 1024 + bi * 64 + c] = tile[c][r];
  }
}

// which==0: xe[row]=<node_t[row],vE>; which==1: xn=bf16(node_next), xk=<.,uK>
__global__ __launch_bounds__(128) void cvt_in_kernel(
    const float* __restrict__ nt, const float* __restrict__ nn,
    const float* __restrict__ vE, const float* __restrict__ uK,
    short* __restrict__ xn, float* __restrict__ xe, float* __restrict__ xk) {
  int row = blockIdx.x, which = blockIdx.y, t = threadIdx.x;
  const float* src = (which ? nn : nt) + (size_t)row * 1024 + t * 8;
  float4 v0 = *(const float4*)src;
  float4 v1 = *(const float4*)(src + 4);
  float a;
  if (which) {
    bfx8 o;
    o[0] = (short)f2bf(v0.x); o[1] = (short)f2bf(v0.y);
    o[2] = (short)f2bf(v0.z); o[3] = (short)f2bf(v0.w);
    o[4] = (short)f2bf(v1.x); o[5] = (short)f2bf(v1.y);
    o[6] = (short)f2bf(v1.z); o[7] = (short)f2bf(v1.w);
    *(bfx8*)(xn + (size_t)row * 1024 + t * 8) = o;
    const float4* uv = (const float4*)(uK + t * 8);
    float4 e0 = uv[0], e1 = uv[1];
    a = v0.x * e0.x + v0.y * e0.y + v0.z * e0.z + v0.w * e0.w +
        v1.x * e1.x + v1.y * e1.y + v1.z * e1.z + v1.w * e1.w;
  } else {
    const float4* ev = (const float4*)(vE + t * 8);
    float4 e0 = ev[0], e1 = ev[1];
    a = v0.x * e0.x + v0.y * e0.y + v0.z * e0.z + v0.w * e0.w +
        v1.x * e1.x + v1.y * e1.y + v1.z * e1.z + v1.w * e1.w;
  }
#pragma unroll
  for (int off = 32; off > 0; off >>= 1) a += __shfl_down(a, off, 64);
  __shared__ float r2[2];
  if ((t & 63) == 0) r2[t >> 6] = a;
  __syncthreads();
  if (t == 0) (which ? xk : xe)[row] = r2[0] + r2[1];
}

// M1 = wqT@wkT^T (z=0) and M2 = wo@wvT^T (z=1); 1024^3, 128x128 tiles.
__global__ __launch_bounds__(256) void gemm_pre(
    const short* __restrict__ A0, const short* __restrict__ B0,
    short* __restrict__ D0, const short* __restrict__ A1,
    const short* __restrict__ B1, short* __restrict__ D1) {
  const short* A = blockIdx.z ? A1 : A0;
  const short* B = blockIdx.z ? B1 : B0;
  short* D = blockIdx.z ? D1 : D0;
  __shared__ short sA[128 * 64];
  __shared__ short sB[128 * 64];
  int tid = threadIdx.x, lane = tid & 63, w = tid >> 6;
  int wm = w >> 1, wn = w & 1;
  int bx = blockIdx.x, by = blockIdx.y;
  f32x4 acc[4][4] = {};
  int lrow = lane & 15, lk = (lane >> 4) * 8;
  int srow = lane >> 3, scol = (lane & 7) * 8;
  const short* Ag = A + (size_t)by * 128 * 1024;
  const short* Bg = B + (size_t)bx * 128 * 1024;
  for (int k0 = 0; k0 < 1024; k0 += 64) {
#pragma unroll
    for (int i = 0; i < 4; ++i) {
      int c = w * 4 + i;
      gload16(Ag + (size_t)(c * 8 + srow) * 1024 + k0 + scol, sA + c * 512);
      gload16(Bg + (size_t)(c * 8 + srow) * 1024 + k0 + scol, sB + c * 512);
    }
    __syncthreads();
#pragma unroll
    for (int kk = 0; kk < 64; kk += 32) {
      bfx8 af[4], bfr[4];
#pragma unroll
      for (int mi = 0; mi < 4; ++mi)
        af[mi] = *(const bfx8*)(sA + (wm * 64 + mi * 16 + lrow) * 64 + kk + lk);
#pragma unroll
      for (int nj = 0; nj < 4; ++nj)
        bfr[nj] = *(const bfx8*)(sB + (wn * 64 + nj * 16 + lrow) * 64 + kk + lk);
#pragma unroll
      for (int mi = 0; mi < 4; ++mi)
#pragma unroll
        for (int nj = 0; nj < 4; ++nj)
          acc[mi][nj] = __builtin_amdgcn_mfma_f32_16x16x32_bf16(
              af[mi], bfr[nj], acc[mi][nj], 0, 0, 0);
    }
    __syncthreads();
  }
  int r0 = by * 128 + wm * 64, cb = bx * 128 + wn * 64;
#pragma unroll
  for (int mi = 0; mi < 4; ++mi)
#pragma unroll
    for (int nj = 0; nj < 4; ++nj) {
      int col = cb + nj * 16 + lrow;
#pragma unroll
      for (int r = 0; r < 4; ++r) {
        int row = r0 + mi * 16 + (lane >> 4) * 4 + r;
        D[(size_t)row * 1024 + col] = (short)f2bf(acc[mi][nj][r]);
      }
    }
}

// Fused main GEMM: D = xn @ Bf^T, Bf=[M1;M2] (2048x1024), bias2=[uQ;bvw].
// bx<8  -> t-half: sPart[row,bx*2+wn] = 64-col partial of <node_t[row],t[row]>
// bx>=8 -> vw store (bf16). 1-D grid 2048, XCD-chunked swizzle.
__global__ __launch_bounds__(256) void gemm_main(
    const short* __restrict__ A, const short* __restrict__ Bf,
    const float* __restrict__ bias2, const float* __restrict__ nodet,
    float* __restrict__ sPart, short* __restrict__ vw) {
  __shared__ short sA[128 * 64];
  __shared__ short sB[128 * 64];
  int tid = threadIdx.x, lane = tid & 63, w = tid >> 6;
  int wm = w >> 1, wn = w & 1;
  int wg = blockIdx.x;
  int work = (wg & 7) * 256 + (wg >> 3);  // XCD gets 256 contiguous works
  int by = work >> 4, bx = work & 15;     // 16 consecutive works share A panel
  f32x4 acc[4][4] = {};
  int lrow = lane & 15, lk = (lane >> 4) * 8;
  int srow = lane >> 3, scol = (lane & 7) * 8;
  const short* Ag = A + (size_t)by * 128 * 1024;
  const short* Bg = Bf + (size_t)bx * 128 * 1024;
  for (int k0 = 0; k0 < 1024; k0 += 64) {
#pragma unroll
    for (int i = 0; i < 4; ++i) {
      int c = w * 4 + i;
      gload16(Ag + (size_t)(c * 8 + srow) * 1024 + k0 + scol, sA + c * 512);
      gload16(Bg + (size_t)(c * 8 + srow) * 1024 + k0 + scol, sB + c * 512);
    }
    __syncthreads();
#pragma unroll
    for (int kk = 0; kk < 64; kk += 32) {
      bfx8 af[4], bfr[4];
#pragma unroll
      for (int mi = 0; mi < 4; ++mi)
        af[mi] = *(const bfx8*)(sA + (wm * 64 + mi * 16 + lrow) * 64 + kk + lk);
#pragma unroll
      for (int nj = 0; nj < 4; ++nj)
        bfr[nj] = *(const bfx8*)(sB + (wn * 64 + nj * 16 + lrow) * 64 + kk + lk);
#pragma unroll
      for (int mi = 0; mi < 4; ++mi)
#pragma unroll
        for (int nj = 0; nj < 4; ++nj)
          acc[mi][nj] = __builtin_amdgcn_mfma_f32_16x16x32_bf16(
              af[mi], bfr[nj], acc[mi][nj], 0, 0, 0);
    }
    __syncthreads();
  }
  int r0 = by * 128 + wm * 64;
  int cb = bx * 128 + wn * 64;  // column in [0,2048)
  if (bx < 8) {
    float bias_nj[4];
#pragma unroll
    for (int nj = 0; nj < 4; ++nj) bias_nj[nj] = bias2[cb + nj * 16 + lrow];
#pragma unroll
    for (int mi = 0; mi < 4; ++mi) {
#pragma unroll
      for (int r = 0; r < 4; ++r) {
        int row = r0 + mi * 16 + (lane >> 4) * 4 + r;
        const float* xr = nodet + (size_t)row * 1024;
        float v = 0.f;
#pragma unroll
        for (int nj = 0; nj < 4; ++nj) {
          int col = cb + nj * 16 + lrow;
          v += (acc[mi][nj][r] + bias_nj[nj]) * xr[col];
        }
        v += __shfl_xor(v, 1, 64);
        v += __shfl_xor(v, 2, 64);
        v += __shfl_xor(v, 4, 64);
        v += __shfl_xor(v, 8, 64);
        if (lrow == 0) sPart[(size_t)row * 16 + bx * 2 + wn] = v;
      }
    }
  } else {
#pragma unroll
    for (int mi = 0; mi < 4; ++mi)
#pragma unroll
      for (int nj = 0; nj < 4; ++nj) {
        int col = cb + nj * 16 + lrow;
        float bv = bias2[col];
        int colv = col - 1024;
#pragma unroll
        for (int r = 0; r < 4; ++r) {
          int row = r0 + mi * 16 + (lane >> 4) * 4 + r;
          vw[(size_t)row * 1024 + colv] = (short)f2bf(acc[mi][nj][r] + bv);
        }
      }
  }
}

// Per n: s[b] = sum_16 sPart + xk + c1; dg = softmax_b(s/128). 64 threads.
__global__ __launch_bounds__(64) void sdiag_kernel(
    const float* __restrict__ sPart, const float* __restrict__ xk,
    const float* __restrict__ c1p, float* __restrict__ dg) {
  int n = blockIdx.x, lane = threadIdx.x;
  int b = lane >> 3, j = lane & 7;
  size_t row = (size_t)b * N_SEQ + n;
  float v = sPart[row * 16 + j * 2] + sPart[row * 16 + j * 2 + 1];
  v += __shfl_xor(v, 1, 64);
  v += __shfl_xor(v, 2, 64);
  v += __shfl_xor(v, 4, 64);
  float s = v + xk[row] + c1p[0];
  float m = s;
  m = fmaxf(m, __shfl_xor(m, 8, 64));
  m = fmaxf(m, __shfl_xor(m, 16, 64));
  m = fmaxf(m, __shfl_xor(m, 32, 64));
  float e = expf((s - m) * (1.0f / 128.0f));
  float sum = e;
  sum += __shfl_xor(sum, 8, 64);
  sum += __shfl_xor(sum, 16, 64);
  sum += __shfl_xor(sum, 32, 64);
  if (j == 0) dg[row] = e / sum;
}

// out[row] = xe[row] + c0 + sum_c gelu(dg*vw[row,c] + bO[c]) * vN[c]
__global__ __launch_bounds__(256) void out_kernel(
    const short* __restrict__ vw, const float* __restrict__ dg,
    const float* __restrict__ xe, const float* __restrict__ vN,
    const float* __restrict__ bO, const float* __restrict__ c0p,
    float* __restrict__ out) {
  int n = blockIdx.x, t = threadIdx.x;
  __shared__ float red[4];
  float4 bo = ((const float4*)bO)[t];
  float4 vn = ((const float4*)vN)[t];
  float c0 = c0p[0];
#pragma unroll
  for (int b = 0; b < 8; ++b) {
    size_t row = (size_t)b * N_SEQ + n;
    float d = dg[row];
    s16x4 vv = *(const s16x4*)(vw + row * 1024 + t * 4);
    float g, a = 0.f;
    g = fmaf(d, bf2f(vv[0]), bo.x); a += gelu_exact(g) * vn.x;
    g = fmaf(d, bf2f(vv[1]), bo.y); a += gelu_exact(g) * vn.y;
    g = fmaf(d, bf2f(vv[2]), bo.z); a += gelu_exact(g) * vn.z;
    g = fmaf(d, bf2f(vv[3]), bo.w); a += gelu_exact(g) * vn.w;
    float tot = blk_sum(a, red, t);
    if (t == 0) out[row] = xe[row] + c0 + tot;
  }
}

// ---------------------------------------------------------------------------
extern "C" void kernel_launch(void* const* d_in, const int* in_sizes, int n_in,
                              void* d_out, int out_size, void* d_ws,
                              size_t ws_size, hipStream_t stream) {
  const float* nt  = (const float*)d_in[0];
  const float* nn  = (const float*)d_in[1];
  const float* WQ  = (const float*)d_in[2];
  const float* bQ  = (const float*)d_in[3];
  const float* WK  = (const float*)d_in[4];
  const float* bK  = (const float*)d_in[5];
  const float* WV  = (const float*)d_in[6];
  const float* bV  = (const float*)d_in[7];
  const float* WO  = (const float*)d_in[8];
  const float* bO  = (const float*)d_in[9];
  const float* WE  = (const float*)d_in[10];
  const float* WEb = (const float*)d_in[11];
  const float* WN  = (const float*)d_in[12];
  const float* WNb = (const float*)d_in[13];
  const float* wa  = (const float*)d_in[14];
  const float* WAb = (const float*)d_in[15];
  float* out = (float*)d_out;

  char* w = (char*)d_ws;
  size_t o = 0;
  const size_t BIG = (size_t)M_TOT * 1024 * 2;          // 33.55 MB
  short* xn    = (short*)(w + o); o += BIG;
  short* vw    = (short*)(w + o); o += BIG;
  short* Bf    = (short*)(w + o); o += (size_t)2048 * 1024 * 2;  // [M1;M2]
  short* wqT   = (short*)(w + o); o += 2097152;
  short* wkT   = (short*)(w + o); o += 2097152;
  short* wvT   = (short*)(w + o); o += 2097152;
  short* wo    = (short*)(w + o); o += 2097152;
  float* sPart = (float*)(w + o); o += (size_t)M_TOT * 16 * 4;   // 1 MB
  float* bias2 = (float*)(w + o); o += 8192;            // [uQ(1024); bvw(1024)]
  float* vE    = (float*)(w + o); o += 4096;
  float* vN    = (float*)(w + o); o += 4096;
  float* uK    = (float*)(w + o); o += 4096;
  float* xe    = (float*)(w + o); o += 65536;
  float* xk    = (float*)(w + o); o += 65536;
  float* dg    = (float*)(w + o); o += 65536;
  float* c0    = (float*)(w + o); o += 256;
  float* c1    = (float*)(w + o); o += 256;
  (void)ws_size; (void)in_sizes; (void)n_in; (void)out_size;

  cvt_wT_kernel<<<dim3(16, 16, 4), 256, 0, stream>>>(WQ, WK, WV, WO,
                                                     wqT, wkT, wvT, wo);
  colred_kernel<<<dim3(4, 5), 256, 0, stream>>>(WE, WN, WQ, WK, wa, bQ, bK,
                                                WEb, WNb, WAb, vE, vN,
                                                bias2, uK, c0, c1);
  rowdot_kernel<<<1024, 256, 0, stream>>>(WO, bV, bias2 + 1024);
  cvt_in_kernel<<<dim3(M_TOT, 2), 128, 0, stream>>>(nt, nn, vE, uK,
                                                    xn, xe, xk);
  gemm_pre<<<dim3(8, 8, 2), 256, 0, stream>>>(wqT, wkT, Bf,
                                              wo, wvT, Bf + 1048576);
  gemm_main<<<2048, 256, 0, stream>>>(xn, Bf, bias2, nt, sPart, vw);
  sdiag_kernel<<<N_SEQ, 64, 0, stream>>>(sPart, xk, c1, dg);
  out_kernel<<<N_SEQ, 256, 0, stream>>>(vw, dg, xe, vN, bO, c0, out);
}

// Round 3
// 198.358 us; speedup vs baseline: 1.7142x; 1.1160x over previous
//
#include <hip/hip_runtime.h>
#include <cstdint>
#include <cstddef>

// ---------------------------------------------------------------------------
// Flow_24429773980225 — round 3: 256^2 8-wave counted-vmcnt GEMM (T2+T3/T4+T5).
//   s[r]  = <node_t[r], t[r]> + <x_n[r], uK> + c1,  t = x_n@M1^T + uQ
//   M1    = WQ^T WK,  uQ = WQ^T bK,  uK = WK^T bQ,  c1 = <bQ,bK>
//   dg    = softmax_b(s/128)
//   vw    = x_n@M2^T + bvw,  M2 = WO·WV,  bvw = WO·bV
//   out[r]= <node_t[r], vE> + c0 + sum_c gelu(dg[r]*vw[r,c] + bO[c])·vN[c]
// One fused [16384,1024]x[2048,1024]^T bf16 GEMM; t-half epilogue computes the
// s row-dot in-register. GEMM: 256x256 tile, BK=64, 8 waves, dbuf LDS with
// XOR-swizzle (inverse-swizzled global_load_lds source), vmcnt(8) pipeline,
// 4 MFMA phases x 16 MFMA with setprio, XCD-chunked block swizzle.
// ---------------------------------------------------------------------------

typedef __attribute__((ext_vector_type(8))) short bfx8;   // 8 bf16
typedef __attribute__((ext_vector_type(4))) short s16x4;  // 4 bf16
typedef __attribute__((ext_vector_type(4))) float f32x4;  // MFMA acc

#define N_SEQ 2048
#define M_TOT 16384   // B*N
#define NT 16         // K / 64

__device__ __forceinline__ unsigned short f2bf(float f) {
  unsigned int u = __float_as_uint(f);
  return (unsigned short)((u + 0x7fffu + ((u >> 16) & 1u)) >> 16);  // RNE
}
__device__ __forceinline__ float bf2f(short s) {
  return __uint_as_float(((unsigned int)(unsigned short)s) << 16);
}
__device__ __forceinline__ float gelu_exact(float g) {
  return 0.5f * g * (1.0f + erff(g * 0.70710678118654752f));
}
__device__ __forceinline__ void gload16(const void* g, void* l) {
  __builtin_amdgcn_global_load_lds(
      (const __attribute__((address_space(1))) unsigned int*)g,
      (__attribute__((address_space(3))) unsigned int*)(unsigned int)(uintptr_t)l,
      16, 0, 0);
}
__device__ __forceinline__ float blk_sum(float v, float* red, int t) {
#pragma unroll
  for (int o = 32; o > 0; o >>= 1) v += __shfl_down(v, o, 64);
  __syncthreads();
  if ((t & 63) == 0) red[t >> 6] = v;
  __syncthreads();
  return red[0] + red[1] + red[2] + red[3];
}

// --------------------------- small precomputes -----------------------------
__global__ __launch_bounds__(256) void colred_kernel(
    const float* __restrict__ WE, const float* __restrict__ WN,
    const float* __restrict__ WQ, const float* __restrict__ WK,
    const float* __restrict__ wa, const float* __restrict__ bQ,
    const float* __restrict__ bK, const float* __restrict__ WEb,
    const float* __restrict__ WNb, const float* __restrict__ WAb,
    float* __restrict__ vE, float* __restrict__ vN,
    float* __restrict__ uQ, float* __restrict__ uK,
    float* __restrict__ c0, float* __restrict__ c1) {
  int y = blockIdx.y;
  if (y < 4) {
    const float* M = y == 0 ? WE : y == 1 ? WN : y == 2 ? WQ : WK;
    const float* wv = (y < 2) ? wa : (y == 2 ? bK : bQ);
    float* dst = y == 0 ? vE : y == 1 ? vN : y == 2 ? uQ : uK;
    int h = blockIdx.x * 256 + threadIdx.x;
    float a = 0.f;
    for (int o = 0; o < 1024; ++o) a += wv[o] * M[(size_t)o * 1024 + h];
    dst[h] = a;
  } else if (blockIdx.x < 2) {
    int t = threadIdx.x;
    float a = 0.f;
    if (blockIdx.x == 0)
      for (int i = t; i < 1024; i += 256) a += wa[i] * (WEb[i] + WNb[i]);
    else
      for (int i = t; i < 1024; i += 256) a += bQ[i] * bK[i];
#pragma unroll
    for (int o = 32; o > 0; o >>= 1) a += __shfl_down(a, o, 64);
    __shared__ float r4[4];
    if ((t & 63) == 0) r4[t >> 6] = a;
    __syncthreads();
    if (t == 0) {
      float tot = r4[0] + r4[1] + r4[2] + r4[3];
      if (blockIdx.x == 0) c0[0] = tot + WAb[0];
      else c1[0] = tot;
    }
  }
}

// bvw[r] = <WO[r,:], bV>
__global__ __launch_bounds__(256) void rowdot_kernel(
    const float* __restrict__ WO, const float* __restrict__ bV,
    float* __restrict__ bvw) {
  int r = blockIdx.x, t = threadIdx.x;
  __shared__ float red[4];
  float4 wv = ((const float4*)(WO + (size_t)r * 1024))[t];
  float4 bv = ((const float4*)bV)[t];
  float a = wv.x * bv.x + wv.y * bv.y + wv.z * bv.z + wv.w * bv.w;
  float tot = blk_sum(a, red, t);
  if (t == 0) bvw[r] = tot;
}

// z 0..2: bf16 TRANSPOSED converts WQ->wqT, WK->wkT, WV->wvT; z==3: WO plain.
__global__ __launch_bounds__(256) void cvt_wT_kernel(
    const float* __restrict__ WQ, const float* __restrict__ WK,
    const float* __restrict__ WV, const float* __restrict__ WO,
    short* __restrict__ wqT, short* __restrict__ wkT,
    short* __restrict__ wvT, short* __restrict__ wo) {
  int bi = blockIdx.x, bj = blockIdx.y, z = blockIdx.z, t = threadIdx.x;
  const float* src = z == 0 ? WQ : z == 1 ? WK : z == 2 ? WV : WO;
  if (z == 3) {
#pragma unroll
    for (int i = 0; i < 16; ++i) {
      int lin = i * 256 + t, r = lin >> 6, c = lin & 63;
      size_t idx = (size_t)(bi * 64 + r) * 1024 + bj * 64 + c;
      wo[idx] = (short)f2bf(src[idx]);
    }
    return;
  }
  __shared__ short tile[64][65];
  short* dst = z == 0 ? wqT : z == 1 ? wkT : wvT;
#pragma unroll
  for (int i = 0; i < 16; ++i) {
    int lin = i * 256 + t, r = lin >> 6, c = lin & 63;
    tile[r][c] = (short)f2bf(src[(size_t)(bi * 64 + r) * 1024 + bj * 64 + c]);
  }
  __syncthreads();
#pragma unroll
  for (int i = 0; i < 16; ++i) {
    int lin = i * 256 + t, r = lin >> 6, c = lin & 63;
    dst[(size_t)(bj * 64 + r) * 1024 + bi * 64 + c] = tile[c][r];
  }
}

// which==0: xe[row]=<node_t[row],vE>; which==1: xn=bf16(node_next), xk=<.,uK>
__global__ __launch_bounds__(128) void cvt_in_kernel(
    const float* __restrict__ nt, const float* __restrict__ nn,
    const float* __restrict__ vE, const float* __restrict__ uK,
    short* __restrict__ xn, float* __restrict__ xe, float* __restrict__ xk) {
  int row = blockIdx.x, which = blockIdx.y, t = threadIdx.x;
  const float* src = (which ? nn : nt) + (size_t)row * 1024 + t * 8;
  float4 v0 = *(const float4*)src;
  float4 v1 = *(const float4*)(src + 4);
  float a;
  if (which) {
    bfx8 o;
    o[0] = (short)f2bf(v0.x); o[1] = (short)f2bf(v0.y);
    o[2] = (short)f2bf(v0.z); o[3] = (short)f2bf(v0.w);
    o[4] = (short)f2bf(v1.x); o[5] = (short)f2bf(v1.y);
    o[6] = (short)f2bf(v1.z); o[7] = (short)f2bf(v1.w);
    *(bfx8*)(xn + (size_t)row * 1024 + t * 8) = o;
    const float4* uv = (const float4*)(uK + t * 8);
    float4 e0 = uv[0], e1 = uv[1];
    a = v0.x * e0.x + v0.y * e0.y + v0.z * e0.z + v0.w * e0.w +
        v1.x * e1.x + v1.y * e1.y + v1.z * e1.z + v1.w * e1.w;
  } else {
    const float4* ev = (const float4*)(vE + t * 8);
    float4 e0 = ev[0], e1 = ev[1];
    a = v0.x * e0.x + v0.y * e0.y + v0.z * e0.z + v0.w * e0.w +
        v1.x * e1.x + v1.y * e1.y + v1.z * e1.z + v1.w * e1.w;
  }
#pragma unroll
  for (int off = 32; off > 0; off >>= 1) a += __shfl_down(a, off, 64);
  __shared__ float r2[2];
  if ((t & 63) == 0) r2[t >> 6] = a;
  __syncthreads();
  if (t == 0) (which ? xk : xe)[row] = r2[0] + r2[1];
}

// M1 = wqT@wkT^T (z=0) and M2 = wo@wvT^T (z=1); 1024^3, 128x128 tiles (m97).
__global__ __launch_bounds__(256) void gemm_pre(
    const short* __restrict__ A0, const short* __restrict__ B0,
    short* __restrict__ D0, const short* __restrict__ A1,
    const short* __restrict__ B1, short* __restrict__ D1) {
  const short* A = blockIdx.z ? A1 : A0;
  const short* B = blockIdx.z ? B1 : B0;
  short* D = blockIdx.z ? D1 : D0;
  __shared__ short sA[128 * 64];
  __shared__ short sB[128 * 64];
  int tid = threadIdx.x, lane = tid & 63, w = tid >> 6;
  int wm = w >> 1, wn = w & 1;
  int bx = blockIdx.x, by = blockIdx.y;
  f32x4 acc[4][4] = {};
  int lrow = lane & 15, lk = (lane >> 4) * 8;
  int srow = lane >> 3, scol = (lane & 7) * 8;
  const short* Ag = A + (size_t)by * 128 * 1024;
  const short* Bg = B + (size_t)bx * 128 * 1024;
  for (int k0 = 0; k0 < 1024; k0 += 64) {
#pragma unroll
    for (int i = 0; i < 4; ++i) {
      int c = w * 4 + i;
      gload16(Ag + (size_t)(c * 8 + srow) * 1024 + k0 + scol, sA + c * 512);
      gload16(Bg + (size_t)(c * 8 + srow) * 1024 + k0 + scol, sB + c * 512);
    }
    __syncthreads();
#pragma unroll
    for (int kk = 0; kk < 64; kk += 32) {
      bfx8 af[4], bfr[4];
#pragma unroll
      for (int mi = 0; mi < 4; ++mi)
        af[mi] = *(const bfx8*)(sA + (wm * 64 + mi * 16 + lrow) * 64 + kk + lk);
#pragma unroll
      for (int nj = 0; nj < 4; ++nj)
        bfr[nj] = *(const bfx8*)(sB + (wn * 64 + nj * 16 + lrow) * 64 + kk + lk);
#pragma unroll
      for (int mi = 0; mi < 4; ++mi)
#pragma unroll
        for (int nj = 0; nj < 4; ++nj)
          acc[mi][nj] = __builtin_amdgcn_mfma_f32_16x16x32_bf16(
              af[mi], bfr[nj], acc[mi][nj], 0, 0, 0);
    }
    __syncthreads();
  }
  int r0 = by * 128 + wm * 64, cb = bx * 128 + wn * 64;
#pragma unroll
  for (int mi = 0; mi < 4; ++mi)
#pragma unroll
    for (int nj = 0; nj < 4; ++nj) {
      int col = cb + nj * 16 + lrow;
#pragma unroll
      for (int r = 0; r < 4; ++r) {
        int row = r0 + mi * 16 + (lane >> 4) * 4 + r;
        D[(size_t)row * 1024 + col] = (short)f2bf(acc[mi][nj][r]);
      }
    }
}

// --------------------- fused main GEMM (256^2, 8 waves) --------------------
// D = xn @ Bf^T, Bf=[M1;M2] rows 0..2047. bx<4 -> s-partials; bx>=4 -> vw.
__global__ __launch_bounds__(512, 2) void gemm_main(
    const short* __restrict__ A, const short* __restrict__ Bf,
    const float* __restrict__ bias2, const float* __restrict__ nodet,
    float* __restrict__ sPart, short* __restrict__ vw) {
  __shared__ short sA[2][16384];  // [buf][256 rows x 64 cols]
  __shared__ short sB[2][16384];
  int tid = threadIdx.x;
  int lane = tid & 63, w = tid >> 6;   // 8 waves
  int wm = w >> 2, wn = w & 3;         // 2 x 4 wave grid
  int wg = blockIdx.x;
  int work = (wg & 7) * 64 + (wg >> 3);  // XCD-chunked, bijective (512%8==0)
  int by = work >> 3, bx = work & 7;
  int lrow = lane & 15, g = lane >> 4;
  int sw0 = g ^ (lrow & 7);            // swizzled slot, kk=0 half
  // staging: chunk c = w*4+i covers rows [c*8, c*8+8); lane l -> row c*8+(l>>3),
  // physical slot l&7 must hold global slot (l&7)^(row&7).
  int sg = (lane & 7) ^ (lane >> 3);
  const short* Agt = A + ((size_t)(by * 256 + w * 32 + (lane >> 3))) * 1024 + sg * 8;
  const short* Bgt = Bf + ((size_t)(bx * 256 + w * 32 + (lane >> 3))) * 1024 + sg * 8;

  f32x4 acc[8][4] = {};

  auto stage = [&](int buf, int kt) {
    const short* ag = Agt + kt * 64;
    const short* bg = Bgt + kt * 64;
    short* la = &sA[buf][w * 2048];
    short* lb = &sB[buf][w * 2048];
#pragma unroll
    for (int i = 0; i < 4; ++i) {
      gload16(ag + i * 8192, la + i * 512);
      gload16(bg + i * 8192, lb + i * 512);
    }
  };

  stage(0, 0);
  int cur = 0;
  for (int kt = 0; kt < NT; ++kt) {
    if (kt + 1 < NT) {
      stage(cur ^ 1, kt + 1);
      asm volatile("s_waitcnt vmcnt(8)" ::: "memory");  // own 8 for buf[cur] done
    } else {
      asm volatile("s_waitcnt vmcnt(0)" ::: "memory");
    }
    __builtin_amdgcn_sched_barrier(0);
    __builtin_amdgcn_s_barrier();      // everyone's buf[cur] loads visible
    __builtin_amdgcn_sched_barrier(0);

    const short* sa = &sA[cur][0];
    const short* sb = &sB[cur][0];
    int brow = wn * 64 + lrow;
    int arow = wm * 128 + lrow;
    // B preload: 8 x ds_read_b128 held in regs across the 4 phases
    bfx8 bq[4][2];
#pragma unroll
    for (int nj = 0; nj < 4; ++nj) {
      bq[nj][0] = *(const bfx8*)(sb + (brow + nj * 16) * 64 + sw0 * 8);
      bq[nj][1] = *(const bfx8*)(sb + (brow + nj * 16) * 64 + (sw0 ^ 4) * 8);
    }
#pragma unroll
    for (int q = 0; q < 4; ++q) {  // 4 phases x 16 MFMA
      bfx8 a00 = *(const bfx8*)(sa + (arow + (2 * q) * 16) * 64 + sw0 * 8);
      bfx8 a01 = *(const bfx8*)(sa + (arow + (2 * q) * 16) * 64 + (sw0 ^ 4) * 8);
      bfx8 a10 = *(const bfx8*)(sa + (arow + (2 * q + 1) * 16) * 64 + sw0 * 8);
      bfx8 a11 = *(const bfx8*)(sa + (arow + (2 * q + 1) * 16) * 64 + (sw0 ^ 4) * 8);
      __builtin_amdgcn_s_setprio(1);
#pragma unroll
      for (int nj = 0; nj < 4; ++nj) {
        acc[2 * q][nj] = __builtin_amdgcn_mfma_f32_16x16x32_bf16(
            a00, bq[nj][0], acc[2 * q][nj], 0, 0, 0);
        acc[2 * q][nj] = __builtin_amdgcn_mfma_f32_16x16x32_bf16(
            a01, bq[nj][1], acc[2 * q][nj], 0, 0, 0);
        acc[2 * q + 1][nj] = __builtin_amdgcn_mfma_f32_16x16x32_bf16(
            a10, bq[nj][0], acc[2 * q + 1][nj], 0, 0, 0);
        acc[2 * q + 1][nj] = __builtin_amdgcn_mfma_f32_16x16x32_bf16(
            a11, bq[nj][1], acc[2 * q + 1][nj], 0, 0, 0);
      }
      __builtin_amdgcn_s_setprio(0);
    }
    __builtin_amdgcn_sched_barrier(0);
    __builtin_amdgcn_s_barrier();      // all reads of buf[cur] done
    __builtin_amdgcn_sched_barrier(0);
    cur ^= 1;
  }

  int row0 = by * 256 + wm * 128;
  int cb = bx * 256 + wn * 64;  // column base in [0,2048)
  if (bx < 4) {
    // t-half: per-row 64-col partial of <node_t[row], t[row]+uQ>
    float bias_nj[4];
#pragma unroll
    for (int nj = 0; nj < 4; ++nj) bias_nj[nj] = bias2[cb + nj * 16 + lrow];
    int px = bx * 4 + wn;  // 16 partials per row
#pragma unroll
    for (int mi = 0; mi < 8; ++mi) {
#pragma unroll
      for (int r = 0; r < 4; ++r) {
        int row = row0 + mi * 16 + g * 4 + r;
        const float* xr = nodet + (size_t)row * 1024;
        float v = 0.f;
#pragma unroll
        for (int nj = 0; nj < 4; ++nj)
          v += (acc[mi][nj][r] + bias_nj[nj]) * xr[cb + nj * 16 + lrow];
        v += __shfl_xor(v, 1, 64);
        v += __shfl_xor(v, 2, 64);
        v += __shfl_xor(v, 4, 64);
        v += __shfl_xor(v, 8, 64);
        if (lrow == 0) sPart[(size_t)row * 16 + px] = v;
      }
    }
  } else {
#pragma unroll
    for (int mi = 0; mi < 8; ++mi)
#pragma unroll
      for (int nj = 0; nj < 4; ++nj) {
        int colv = cb - 1024 + nj * 16 + lrow;
        float bv = bias2[1024 + colv];
#pragma unroll
        for (int r = 0; r < 4; ++r) {
          int row = row0 + mi * 16 + g * 4 + r;
          vw[(size_t)row * 1024 + colv] = (short)f2bf(acc[mi][nj][r] + bv);
        }
      }
  }
}

// Per n: s[b] = sum_16 sPart + xk + c1; dg = softmax_b(s/128). 64 threads.
__global__ __launch_bounds__(64) void sdiag_kernel(
    const float* __restrict__ sPart, const float* __restrict__ xk,
    const float* __restrict__ c1p, float* __restrict__ dg) {
  int n = blockIdx.x, lane = threadIdx.x;
  int b = lane >> 3, j = lane & 7;
  size_t row = (size_t)b * N_SEQ + n;
  float v = sPart[row * 16 + j * 2] + sPart[row * 16 + j * 2 + 1];
  v += __shfl_xor(v, 1, 64);
  v += __shfl_xor(v, 2, 64);
  v += __shfl_xor(v, 4, 64);
  float s = v + xk[row] + c1p[0];
  float m = s;
  m = fmaxf(m, __shfl_xor(m, 8, 64));
  m = fmaxf(m, __shfl_xor(m, 16, 64));
  m = fmaxf(m, __shfl_xor(m, 32, 64));
  float e = expf((s - m) * (1.0f / 128.0f));
  float sum = e;
  sum += __shfl_xor(sum, 8, 64);
  sum += __shfl_xor(sum, 16, 64);
  sum += __shfl_xor(sum, 32, 64);
  if (j == 0) dg[row] = e / sum;
}

// out[row] = xe[row] + c0 + sum_c gelu(dg*vw[row,c] + bO[c]) * vN[c]
__global__ __launch_bounds__(256) void out_kernel(
    const short* __restrict__ vw, const float* __restrict__ dg,
    const float* __restrict__ xe, const float* __restrict__ vN,
    const float* __restrict__ bO, const float* __restrict__ c0p,
    float* __restrict__ out) {
  int n = blockIdx.x, t = threadIdx.x;
  __shared__ float red[4];
  float4 bo = ((const float4*)bO)[t];
  float4 vn = ((const float4*)vN)[t];
  float c0 = c0p[0];
#pragma unroll
  for (int b = 0; b < 8; ++b) {
    size_t row = (size_t)b * N_SEQ + n;
    float d = dg[row];
    s16x4 vv = *(const s16x4*)(vw + row * 1024 + t * 4);
    float gx, a = 0.f;
    gx = fmaf(d, bf2f(vv[0]), bo.x); a += gelu_exact(gx) * vn.x;
    gx = fmaf(d, bf2f(vv[1]), bo.y); a += gelu_exact(gx) * vn.y;
    gx = fmaf(d, bf2f(vv[2]), bo.z); a += gelu_exact(gx) * vn.z;
    gx = fmaf(d, bf2f(vv[3]), bo.w); a += gelu_exact(gx) * vn.w;
    float tot = blk_sum(a, red, t);
    if (t == 0) out[row] = xe[row] + c0 + tot;
  }
}

// ---------------------------------------------------------------------------
extern "C" void kernel_launch(void* const* d_in, const int* in_sizes, int n_in,
                              void* d_out, int out_size, void* d_ws,
                              size_t ws_size, hipStream_t stream) {
  const float* nt  = (const float*)d_in[0];
  const float* nn  = (const float*)d_in[1];
  const float* WQ  = (const float*)d_in[2];
  const float* bQ  = (const float*)d_in[3];
  const float* WK  = (const float*)d_in[4];
  const float* bK  = (const float*)d_in[5];
  const float* WV  = (const float*)d_in[6];
  const float* bV  = (const float*)d_in[7];
  const float* WO  = (const float*)d_in[8];
  const float* bO  = (const float*)d_in[9];
  const float* WE  = (const float*)d_in[10];
  const float* WEb = (const float*)d_in[11];
  const float* WN  = (const float*)d_in[12];
  const float* WNb = (const float*)d_in[13];
  const float* wa  = (const float*)d_in[14];
  const float* WAb = (const float*)d_in[15];
  float* out = (float*)d_out;

  char* w = (char*)d_ws;
  size_t o = 0;
  const size_t BIG = (size_t)M_TOT * 1024 * 2;          // 33.55 MB
  short* xn    = (short*)(w + o); o += BIG;
  short* vw    = (short*)(w + o); o += BIG;
  short* Bf    = (short*)(w + o); o += (size_t)2048 * 1024 * 2;  // [M1;M2]
  short* wqT   = (short*)(w + o); o += 2097152;
  short* wkT   = (short*)(w + o); o += 2097152;
  short* wvT   = (short*)(w + o); o += 2097152;
  short* wo    = (short*)(w + o); o += 2097152;
  float* sPart = (float*)(w + o); o += (size_t)M_TOT * 16 * 4;   // 1 MB
  float* bias2 = (float*)(w + o); o += 8192;            // [uQ(1024); bvw(1024)]
  float* vE    = (float*)(w + o); o += 4096;
  float* vN    = (float*)(w + o); o += 4096;
  float* uK    = (float*)(w + o); o += 4096;
  float* xe    = (float*)(w + o); o += 65536;
  float* xk    = (float*)(w + o); o += 65536;
  float* dg    = (float*)(w + o); o += 65536;
  float* c0    = (float*)(w + o); o += 256;
  float* c1    = (float*)(w + o); o += 256;
  (void)ws_size; (void)in_sizes; (void)n_in; (void)out_size;

  cvt_wT_kernel<<<dim3(16, 16, 4), 256, 0, stream>>>(WQ, WK, WV, WO,
                                                     wqT, wkT, wvT, wo);
  colred_kernel<<<dim3(4, 5), 256, 0, stream>>>(WE, WN, WQ, WK, wa, bQ, bK,
                                                WEb, WNb, WAb, vE, vN,
                                                bias2, uK, c0, c1);
  rowdot_kernel<<<1024, 256, 0, stream>>>(WO, bV, bias2 + 1024);
  cvt_in_kernel<<<dim3(M_TOT, 2), 128, 0, stream>>>(nt, nn, vE, uK,
                                                    xn, xe, xk);
  gemm_pre<<<dim3(8, 8, 2), 256, 0, stream>>>(wqT, wkT, Bf,
                                              wo, wvT, Bf + 1048576);
  gemm_main<<<512, 512, 0, stream>>>(xn, Bf, bias2, nt, sPart, vw);
  sdiag_kernel<<<N_SEQ, 64, 0, stream>>>(sPart, xk, c1, dg);
  out_kernel<<<N_SEQ, 256, 0, stream>>>(vw, dg, xe, vN, bO, c0, out);
}

// Round 4
// 180.329 us; speedup vs baseline: 1.8856x; 1.1000x over previous
//
#include <hip/hip_runtime.h>
#include <cstdint>
#include <cstddef>

// ---------------------------------------------------------------------------
// Flow_24429773980225 — round 4: 4-phase interior schedule + epilogue-fused xe.
//   s[r]  = <node_t[r], t[r]> + <x_n[r], uK> + c1,  t = x_n@M1^T + uQ
//   M1    = WQ^T WK,  uQ = WQ^T bK,  uK = WK^T bQ,  c1 = <bQ,bK>
//   dg    = softmax_b(s/128)
//   vw    = x_n@M2^T + bvw,  M2 = WO·WV,  bvw = WO·bV
//   out[r]= <node_t[r], vE> + c0 + sum_c gelu(dg[r]*vw[r,c] + bO[c])·vN[c]
// One fused [16384,1024]x[2048,1024]^T bf16 GEMM (256^2 tile, 8 waves, dbuf,
// XOR-swizzled LDS, vmcnt(8) depth-1 prefetch, 4 MFMA phases w/ barriers +
// setprio + A-lookahead). t-half epilogue computes BOTH the s row-dot and the
// xe row-dot from the same node_t read.
// ---------------------------------------------------------------------------

typedef __attribute__((ext_vector_type(8))) short bfx8;   // 8 bf16
typedef __attribute__((ext_vector_type(4))) short s16x4;  // 4 bf16
typedef __attribute__((ext_vector_type(4))) float f32x4;  // MFMA acc

#define N_SEQ 2048
#define M_TOT 16384   // B*N
#define NT 16         // K / 64

__device__ __forceinline__ unsigned short f2bf(float f) {
  unsigned int u = __float_as_uint(f);
  return (unsigned short)((u + 0x7fffu + ((u >> 16) & 1u)) >> 16);  // RNE
}
__device__ __forceinline__ float bf2f(short s) {
  return __uint_as_float(((unsigned int)(unsigned short)s) << 16);
}
__device__ __forceinline__ float gelu_exact(float g) {
  return 0.5f * g * (1.0f + erff(g * 0.70710678118654752f));
}
__device__ __forceinline__ void gload16(const void* g, void* l) {
  __builtin_amdgcn_global_load_lds(
      (const __attribute__((address_space(1))) unsigned int*)g,
      (__attribute__((address_space(3))) unsigned int*)(unsigned int)(uintptr_t)l,
      16, 0, 0);
}
__device__ __forceinline__ float blk_sum(float v, float* red, int t) {
#pragma unroll
  for (int o = 32; o > 0; o >>= 1) v += __shfl_down(v, o, 64);
  __syncthreads();
  if ((t & 63) == 0) red[t >> 6] = v;
  __syncthreads();
  return red[0] + red[1] + red[2] + red[3];
}

// --------------------------- small precomputes -----------------------------
__global__ __launch_bounds__(256) void colred_kernel(
    const float* __restrict__ WE, const float* __restrict__ WN,
    const float* __restrict__ WQ, const float* __restrict__ WK,
    const float* __restrict__ wa, const float* __restrict__ bQ,
    const float* __restrict__ bK, const float* __restrict__ WEb,
    const float* __restrict__ WNb, const float* __restrict__ WAb,
    float* __restrict__ vE, float* __restrict__ vN,
    float* __restrict__ uQ, float* __restrict__ uK,
    float* __restrict__ c0, float* __restrict__ c1) {
  int y = blockIdx.y;
  if (y < 4) {
    const float* M = y == 0 ? WE : y == 1 ? WN : y == 2 ? WQ : WK;
    const float* wv = (y < 2) ? wa : (y == 2 ? bK : bQ);
    float* dst = y == 0 ? vE : y == 1 ? vN : y == 2 ? uQ : uK;
    int h = blockIdx.x * 256 + threadIdx.x;
    float a = 0.f;
    for (int o = 0; o < 1024; ++o) a += wv[o] * M[(size_t)o * 1024 + h];
    dst[h] = a;
  } else if (blockIdx.x < 2) {
    int t = threadIdx.x;
    float a = 0.f;
    if (blockIdx.x == 0)
      for (int i = t; i < 1024; i += 256) a += wa[i] * (WEb[i] + WNb[i]);
    else
      for (int i = t; i < 1024; i += 256) a += bQ[i] * bK[i];
#pragma unroll
    for (int o = 32; o > 0; o >>= 1) a += __shfl_down(a, o, 64);
    __shared__ float r4[4];
    if ((t & 63) == 0) r4[t >> 6] = a;
    __syncthreads();
    if (t == 0) {
      float tot = r4[0] + r4[1] + r4[2] + r4[3];
      if (blockIdx.x == 0) c0[0] = tot + WAb[0];
      else c1[0] = tot;
    }
  }
}

// bvw[r] = <WO[r,:], bV>
__global__ __launch_bounds__(256) void rowdot_kernel(
    const float* __restrict__ WO, const float* __restrict__ bV,
    float* __restrict__ bvw) {
  int r = blockIdx.x, t = threadIdx.x;
  __shared__ float red[4];
  float4 wv = ((const float4*)(WO + (size_t)r * 1024))[t];
  float4 bv = ((const float4*)bV)[t];
  float a = wv.x * bv.x + wv.y * bv.y + wv.z * bv.z + wv.w * bv.w;
  float tot = blk_sum(a, red, t);
  if (t == 0) bvw[r] = tot;
}

// z 0..2: bf16 TRANSPOSED converts WQ->wqT, WK->wkT, WV->wvT; z==3: WO plain.
__global__ __launch_bounds__(256) void cvt_wT_kernel(
    const float* __restrict__ WQ, const float* __restrict__ WK,
    const float* __restrict__ WV, const float* __restrict__ WO,
    short* __restrict__ wqT, short* __restrict__ wkT,
    short* __restrict__ wvT, short* __restrict__ wo) {
  int bi = blockIdx.x, bj = blockIdx.y, z = blockIdx.z, t = threadIdx.x;
  const float* src = z == 0 ? WQ : z == 1 ? WK : z == 2 ? WV : WO;
  if (z == 3) {
#pragma unroll
    for (int i = 0; i < 16; ++i) {
      int lin = i * 256 + t, r = lin >> 6, c = lin & 63;
      size_t idx = (size_t)(bi * 64 + r) * 1024 + bj * 64 + c;
      wo[idx] = (short)f2bf(src[idx]);
    }
    return;
  }
  __shared__ short tile[64][65];
  short* dst = z == 0 ? wqT : z == 1 ? wkT : wvT;
#pragma unroll
  for (int i = 0; i < 16; ++i) {
    int lin = i * 256 + t, r = lin >> 6, c = lin & 63;
    tile[r][c] = (short)f2bf(src[(size_t)(bi * 64 + r) * 1024 + bj * 64 + c]);
  }
  __syncthreads();
#pragma unroll
  for (int i = 0; i < 16; ++i) {
    int lin = i * 256 + t, r = lin >> 6, c = lin & 63;
    dst[(size_t)(bj * 64 + r) * 1024 + bi * 64 + c] = tile[c][r];
  }
}

// node_next only: xn = bf16(nn), xk[row] = <nn[row], uK>.
__global__ __launch_bounds__(128) void cvt_nn_kernel(
    const float* __restrict__ nn, const float* __restrict__ uK,
    short* __restrict__ xn, float* __restrict__ xk) {
  int row = blockIdx.x, t = threadIdx.x;
  const float* src = nn + (size_t)row * 1024 + t * 8;
  float4 v0 = *(const float4*)src;
  float4 v1 = *(const float4*)(src + 4);
  bfx8 o;
  o[0] = (short)f2bf(v0.x); o[1] = (short)f2bf(v0.y);
  o[2] = (short)f2bf(v0.z); o[3] = (short)f2bf(v0.w);
  o[4] = (short)f2bf(v1.x); o[5] = (short)f2bf(v1.y);
  o[6] = (short)f2bf(v1.z); o[7] = (short)f2bf(v1.w);
  *(bfx8*)(xn + (size_t)row * 1024 + t * 8) = o;
  const float4* uv = (const float4*)(uK + t * 8);
  float4 e0 = uv[0], e1 = uv[1];
  float a = v0.x * e0.x + v0.y * e0.y + v0.z * e0.z + v0.w * e0.w +
            v1.x * e1.x + v1.y * e1.y + v1.z * e1.z + v1.w * e1.w;
#pragma unroll
  for (int off = 32; off > 0; off >>= 1) a += __shfl_down(a, off, 64);
  __shared__ float r2[2];
  if ((t & 63) == 0) r2[t >> 6] = a;
  __syncthreads();
  if (t == 0) xk[row] = r2[0] + r2[1];
}

// M1 = wqT@wkT^T (z=0) and M2 = wo@wvT^T (z=1); 1024^3, 128x128 tiles (m97).
__global__ __launch_bounds__(256) void gemm_pre(
    const short* __restrict__ A0, const short* __restrict__ B0,
    short* __restrict__ D0, const short* __restrict__ A1,
    const short* __restrict__ B1, short* __restrict__ D1) {
  const short* A = blockIdx.z ? A1 : A0;
  const short* B = blockIdx.z ? B1 : B0;
  short* D = blockIdx.z ? D1 : D0;
  __shared__ short sA[128 * 64];
  __shared__ short sB[128 * 64];
  int tid = threadIdx.x, lane = tid & 63, w = tid >> 6;
  int wm = w >> 1, wn = w & 1;
  int bx = blockIdx.x, by = blockIdx.y;
  f32x4 acc[4][4] = {};
  int lrow = lane & 15, lk = (lane >> 4) * 8;
  int srow = lane >> 3, scol = (lane & 7) * 8;
  const short* Ag = A + (size_t)by * 128 * 1024;
  const short* Bg = B + (size_t)bx * 128 * 1024;
  for (int k0 = 0; k0 < 1024; k0 += 64) {
#pragma unroll
    for (int i = 0; i < 4; ++i) {
      int c = w * 4 + i;
      gload16(Ag + (size_t)(c * 8 + srow) * 1024 + k0 + scol, sA + c * 512);
      gload16(Bg + (size_t)(c * 8 + srow) * 1024 + k0 + scol, sB + c * 512);
    }
    __syncthreads();
#pragma unroll
    for (int kk = 0; kk < 64; kk += 32) {
      bfx8 af[4], bfr[4];
#pragma unroll
      for (int mi = 0; mi < 4; ++mi)
        af[mi] = *(const bfx8*)(sA + (wm * 64 + mi * 16 + lrow) * 64 + kk + lk);
#pragma unroll
      for (int nj = 0; nj < 4; ++nj)
        bfr[nj] = *(const bfx8*)(sB + (wn * 64 + nj * 16 + lrow) * 64 + kk + lk);
#pragma unroll
      for (int mi = 0; mi < 4; ++mi)
#pragma unroll
        for (int nj = 0; nj < 4; ++nj)
          acc[mi][nj] = __builtin_amdgcn_mfma_f32_16x16x32_bf16(
              af[mi], bfr[nj], acc[mi][nj], 0, 0, 0);
    }
    __syncthreads();
  }
  int r0 = by * 128 + wm * 64, cb = bx * 128 + wn * 64;
#pragma unroll
  for (int mi = 0; mi < 4; ++mi)
#pragma unroll
    for (int nj = 0; nj < 4; ++nj) {
      int col = cb + nj * 16 + lrow;
#pragma unroll
      for (int r = 0; r < 4; ++r) {
        int row = r0 + mi * 16 + (lane >> 4) * 4 + r;
        D[(size_t)row * 1024 + col] = (short)f2bf(acc[mi][nj][r]);
      }
    }
}

// --------------------- fused main GEMM (256^2, 8 waves) --------------------
// D = xn @ Bf^T, Bf=[M1;M2]. bx<4 -> s+xe partials; bx>=4 -> vw store.
__global__ __launch_bounds__(512, 2) void gemm_main(
    const short* __restrict__ A, const short* __restrict__ Bf,
    const float* __restrict__ bias2, const float* __restrict__ nodet,
    const float* __restrict__ vE, float* __restrict__ sPart,
    float* __restrict__ xePart, short* __restrict__ vw) {
  __shared__ short sA[2][16384];  // [buf][256 rows x 64 cols], XOR-swizzled
  __shared__ short sB[2][16384];
  int tid = threadIdx.x;
  int lane = tid & 63, w = tid >> 6;   // 8 waves
  int wm = w >> 2, wn = w & 3;         // 2 x 4 wave grid
  int wg = blockIdx.x;
  int work = (wg & 7) * 64 + (wg >> 3);  // XCD-chunked, bijective (512%8==0)
  int by = work >> 3, bx = work & 7;
  int lrow = lane & 15, g = lane >> 4;
  int sw0 = g ^ (lrow & 7);            // swizzled slot, kk=0 half
  int sg = (lane & 7) ^ (lane >> 3);   // inverse-swizzled global col slot
  const short* Agt = A + ((size_t)(by * 256 + w * 32 + (lane >> 3))) * 1024 + sg * 8;
  const short* Bgt = Bf + ((size_t)(bx * 256 + w * 32 + (lane >> 3))) * 1024 + sg * 8;

  f32x4 acc[8][4] = {};

  auto stage = [&](int buf, int kt) {
    const short* ag = Agt + kt * 64;
    const short* bg = Bgt + kt * 64;
    short* la = &sA[buf][w * 2048];
    short* lb = &sB[buf][w * 2048];
#pragma unroll
    for (int i = 0; i < 4; ++i) {
      gload16(ag + i * 8192, la + i * 512);
      gload16(bg + i * 8192, lb + i * 512);
    }
  };

  stage(0, 0);
  int arow = wm * 128 + lrow;
  int brow = wn * 64 + lrow;
  for (int kt = 0; kt < NT; ++kt) {
    int cur = kt & 1;
    if (kt + 1 < NT) {
      stage(cur ^ 1, kt + 1);   // buf[cur^1] freed by kt-1's closing barrier
      asm volatile("s_waitcnt vmcnt(8)" ::: "memory");  // tile kt resident
    } else {
      asm volatile("s_waitcnt vmcnt(0)" ::: "memory");
    }
    __builtin_amdgcn_sched_barrier(0);
    __builtin_amdgcn_s_barrier();      // tile kt visible to all waves
    __builtin_amdgcn_sched_barrier(0);

    const short* sa = &sA[cur][0];
    const short* sb = &sB[cur][0];
    // B: all 8 fragments up front (kept across the 4 phases)
    bfx8 bq[4][2];
#pragma unroll
    for (int nj = 0; nj < 4; ++nj) {
      bq[nj][0] = *(const bfx8*)(sb + (brow + nj * 16) * 64 + sw0 * 8);
      bq[nj][1] = *(const bfx8*)(sb + (brow + nj * 16) * 64 + (sw0 ^ 4) * 8);
    }
    // A quadrant 0 (mi=0,1)
    bfx8 a0 = *(const bfx8*)(sa + (arow + 0 * 16) * 64 + sw0 * 8);
    bfx8 a1 = *(const bfx8*)(sa + (arow + 0 * 16) * 64 + (sw0 ^ 4) * 8);
    bfx8 a2 = *(const bfx8*)(sa + (arow + 1 * 16) * 64 + sw0 * 8);
    bfx8 a3 = *(const bfx8*)(sa + (arow + 1 * 16) * 64 + (sw0 ^ 4) * 8);
#pragma unroll
    for (int q = 0; q < 4; ++q) {      // 4 phases x 16 MFMA, A one-phase ahead
      bfx8 n0 = a0, n1 = a1, n2 = a2, n3 = a3;
      if (q < 3) {
        n0 = *(const bfx8*)(sa + (arow + (2 * q + 2) * 16) * 64 + sw0 * 8);
        n1 = *(const bfx8*)(sa + (arow + (2 * q + 2) * 16) * 64 + (sw0 ^ 4) * 8);
        n2 = *(const bfx8*)(sa + (arow + (2 * q + 3) * 16) * 64 + sw0 * 8);
        n3 = *(const bfx8*)(sa + (arow + (2 * q + 3) * 16) * 64 + (sw0 ^ 4) * 8);
      }
      __builtin_amdgcn_s_setprio(1);
#pragma unroll
      for (int nj = 0; nj < 4; ++nj) {
        acc[2 * q][nj] = __builtin_amdgcn_mfma_f32_16x16x32_bf16(
            a0, bq[nj][0], acc[2 * q][nj], 0, 0, 0);
        acc[2 * q][nj] = __builtin_amdgcn_mfma_f32_16x16x32_bf16(
            a1, bq[nj][1], acc[2 * q][nj], 0, 0, 0);
        acc[2 * q + 1][nj] = __builtin_amdgcn_mfma_f32_16x16x32_bf16(
            a2, bq[nj][0], acc[2 * q + 1][nj], 0, 0, 0);
        acc[2 * q + 1][nj] = __builtin_amdgcn_mfma_f32_16x16x32_bf16(
            a3, bq[nj][1], acc[2 * q + 1][nj], 0, 0, 0);
      }
      __builtin_amdgcn_s_setprio(0);
      __builtin_amdgcn_sched_barrier(0);
      __builtin_amdgcn_s_barrier();    // phase boundary (q==3: closes tile)
      __builtin_amdgcn_sched_barrier(0);
      a0 = n0; a1 = n1; a2 = n2; a3 = n3;
    }
  }

  int row0 = by * 256 + wm * 128;
  int cb = bx * 256 + wn * 64;  // column base in [0,2048)
  if (bx < 4) {
    // t-half: per-row 64-col partials of <node_t, t+uQ> AND <node_t, vE>
    float bias_nj[4], ve_nj[4];
#pragma unroll
    for (int nj = 0; nj < 4; ++nj) {
      bias_nj[nj] = bias2[cb + nj * 16 + lrow];
      ve_nj[nj] = vE[cb + nj * 16 + lrow];
    }
    int px = bx * 4 + wn;  // 16 partials per row
#pragma unroll
    for (int mi = 0; mi < 8; ++mi) {
#pragma unroll
      for (int r = 0; r < 4; ++r) {
        int row = row0 + mi * 16 + g * 4 + r;
        const float* xr = nodet + (size_t)row * 1024;
        float v = 0.f, v2 = 0.f;
#pragma unroll
        for (int nj = 0; nj < 4; ++nj) {
          float xv = xr[cb + nj * 16 + lrow];
          v += (acc[mi][nj][r] + bias_nj[nj]) * xv;
          v2 += ve_nj[nj] * xv;
        }
        v += __shfl_xor(v, 1, 64);   v2 += __shfl_xor(v2, 1, 64);
        v += __shfl_xor(v, 2, 64);   v2 += __shfl_xor(v2, 2, 64);
        v += __shfl_xor(v, 4, 64);   v2 += __shfl_xor(v2, 4, 64);
        v += __shfl_xor(v, 8, 64);   v2 += __shfl_xor(v2, 8, 64);
        if (lrow == 0) {
          sPart[(size_t)row * 16 + px] = v;
          xePart[(size_t)row * 16 + px] = v2;
        }
      }
    }
  } else {
#pragma unroll
    for (int mi = 0; mi < 8; ++mi)
#pragma unroll
      for (int nj = 0; nj < 4; ++nj) {
        int colv = cb - 1024 + nj * 16 + lrow;
        float bv = bias2[1024 + colv];
#pragma unroll
        for (int r = 0; r < 4; ++r) {
          int row = row0 + mi * 16 + g * 4 + r;
          vw[(size_t)row * 1024 + colv] = (short)f2bf(acc[mi][nj][r] + bv);
        }
      }
  }
}

// Per n: s[b] = sum_16 sPart + xk + c1; dg = softmax_b(s/128). 64 threads.
__global__ __launch_bounds__(64) void sdiag_kernel(
    const float* __restrict__ sPart, const float* __restrict__ xk,
    const float* __restrict__ c1p, float* __restrict__ dg) {
  int n = blockIdx.x, lane = threadIdx.x;
  int b = lane >> 3, j = lane & 7;
  size_t row = (size_t)b * N_SEQ + n;
  float v = sPart[row * 16 + j * 2] + sPart[row * 16 + j * 2 + 1];
  v += __shfl_xor(v, 1, 64);
  v += __shfl_xor(v, 2, 64);
  v += __shfl_xor(v, 4, 64);
  float s = v + xk[row] + c1p[0];
  float m = s;
  m = fmaxf(m, __shfl_xor(m, 8, 64));
  m = fmaxf(m, __shfl_xor(m, 16, 64));
  m = fmaxf(m, __shfl_xor(m, 32, 64));
  float e = expf((s - m) * (1.0f / 128.0f));
  float sum = e;
  sum += __shfl_xor(sum, 8, 64);
  sum += __shfl_xor(sum, 16, 64);
  sum += __shfl_xor(sum, 32, 64);
  if (j == 0) dg[row] = e / sum;
}

// out[row] = xe[row] + c0 + sum_c gelu(dg*vw[row,c] + bO[c]) * vN[c]
__global__ __launch_bounds__(256) void out_kernel(
    const short* __restrict__ vw, const float* __restrict__ dg,
    const float* __restrict__ xePart, const float* __restrict__ vN,
    const float* __restrict__ bO, const float* __restrict__ c0p,
    float* __restrict__ out) {
  int n = blockIdx.x, t = threadIdx.x;
  __shared__ float red[4];
  __shared__ float xeS[8];
  if (t < 128) {   // gather xe: 8 rows x 16 partials, waves 0-1
    int b = t >> 4, j = t & 15;
    float p = xePart[((size_t)b * N_SEQ + n) * 16 + j];
    p += __shfl_xor(p, 1, 64);
    p += __shfl_xor(p, 2, 64);
    p += __shfl_xor(p, 4, 64);
    p += __shfl_xor(p, 8, 64);
    if (j == 0) xeS[b] = p;
  }
  __syncthreads();
  float4 bo = ((const float4*)bO)[t];
  float4 vn = ((const float4*)vN)[t];
  float c0 = c0p[0];
#pragma unroll
  for (int b = 0; b < 8; ++b) {
    size_t row = (size_t)b * N_SEQ + n;
    float d = dg[row];
    s16x4 vv = *(const s16x4*)(vw + row * 1024 + t * 4);
    float gx, a = 0.f;
    gx = fmaf(d, bf2f(vv[0]), bo.x); a += gelu_exact(gx) * vn.x;
    gx = fmaf(d, bf2f(vv[1]), bo.y); a += gelu_exact(gx) * vn.y;
    gx = fmaf(d, bf2f(vv[2]), bo.z); a += gelu_exact(gx) * vn.z;
    gx = fmaf(d, bf2f(vv[3]), bo.w); a += gelu_exact(gx) * vn.w;
    float tot = blk_sum(a, red, t);
    if (t == 0) out[row] = xeS[b] + c0 + tot;
  }
}

// ---------------------------------------------------------------------------
extern "C" void kernel_launch(void* const* d_in, const int* in_sizes, int n_in,
                              void* d_out, int out_size, void* d_ws,
                              size_t ws_size, hipStream_t stream) {
  const float* nt  = (const float*)d_in[0];
  const float* nn  = (const float*)d_in[1];
  const float* WQ  = (const float*)d_in[2];
  const float* bQ  = (const float*)d_in[3];
  const float* WK  = (const float*)d_in[4];
  const float* bK  = (const float*)d_in[5];
  const float* WV  = (const float*)d_in[6];
  const float* bV  = (const float*)d_in[7];
  const float* WO  = (const float*)d_in[8];
  const float* bO  = (const float*)d_in[9];
  const float* WE  = (const float*)d_in[10];
  const float* WEb = (const float*)d_in[11];
  const float* WN  = (const float*)d_in[12];
  const float* WNb = (const float*)d_in[13];
  const float* wa  = (const float*)d_in[14];
  const float* WAb = (const float*)d_in[15];
  float* out = (float*)d_out;

  char* w = (char*)d_ws;
  size_t o = 0;
  const size_t BIG = (size_t)M_TOT * 1024 * 2;          // 33.55 MB
  short* xn     = (short*)(w + o); o += BIG;
  short* vw     = (short*)(w + o); o += BIG;
  short* Bf     = (short*)(w + o); o += (size_t)2048 * 1024 * 2;  // [M1;M2]
  short* wqT    = (short*)(w + o); o += 2097152;
  short* wkT    = (short*)(w + o); o += 2097152;
  short* wvT    = (short*)(w + o); o += 2097152;
  short* wo     = (short*)(w + o); o += 2097152;
  float* sPart  = (float*)(w + o); o += (size_t)M_TOT * 16 * 4;   // 1 MB
  float* xePart = (float*)(w + o); o += (size_t)M_TOT * 16 * 4;   // 1 MB
  float* bias2  = (float*)(w + o); o += 8192;           // [uQ(1024); bvw(1024)]
  float* vE     = (float*)(w + o); o += 4096;
  float* vN     = (float*)(w + o); o += 4096;
  float* uK     = (float*)(w + o); o += 4096;
  float* xk     = (float*)(w + o); o += 65536;
  float* dg     = (float*)(w + o); o += 65536;
  float* c0     = (float*)(w + o); o += 256;
  float* c1     = (float*)(w + o); o += 256;
  (void)ws_size; (void)in_sizes; (void)n_in; (void)out_size;

  cvt_wT_kernel<<<dim3(16, 16, 4), 256, 0, stream>>>(WQ, WK, WV, WO,
                                                     wqT, wkT, wvT, wo);
  colred_kernel<<<dim3(4, 5), 256, 0, stream>>>(WE, WN, WQ, WK, wa, bQ, bK,
                                                WEb, WNb, WAb, vE, vN,
                                                bias2, uK, c0, c1);
  rowdot_kernel<<<1024, 256, 0, stream>>>(WO, bV, bias2 + 1024);
  cvt_nn_kernel<<<M_TOT, 128, 0, stream>>>(nn, uK, xn, xk);
  gemm_pre<<<dim3(8, 8, 2), 256, 0, stream>>>(wqT, wkT, Bf,
                                              wo, wvT, Bf + 1048576);
  gemm_main<<<512, 512, 0, stream>>>(xn, Bf, bias2, nt, vE,
                                     sPart, xePart, vw);
  sdiag_kernel<<<N_SEQ, 64, 0, stream>>>(sPart, xk, c1, dg);
  out_kernel<<<N_SEQ, 256, 0, stream>>>(vw, dg, xePart, vN, bO, c0, out);
}